// Round 1
// baseline (190.206 us; speedup 1.0000x reference)
//
#include <hip/hip_runtime.h>

#define DIM 64
#define BIN_SHIFT 7                  // 128 nodes per bin
#define NODES_PER_BIN 128
#define MAX_BINS 1024                // ceil(100000/128)=782 <= 1024
#define BIN_CAP 2048                 // mean 1279, sigma ~36 -> 21-sigma margin
#define CHUNK_EDGES 4096             // edges per scatter block (was 2048; halves gcur atomics)
#define GEMM_ROWS 128                // rows per gemm-role block
#define FXSCALE 65536.0f             // fixed-point scale 2^16
#define FXINV (1.0f / 65536.0f)
#define FXBIAS 524288u               // 2^19 per-term bias: v >= -8 guaranteed non-negative term
#define MAGIC 12582912.0f            // 1.5*2^23 RNE float->int magic
#define MAGIC_I 0x4B400000u
#define GCUR_STRIDE 16               // one cacheline per bin counter (de-hotspot reservation)
#define ACC_U64 33                   // u64 per node: 32 used + 1 pad (odd -> bank spread)

// ws layout (256-aligned):
// flag | gcur[MAX_BINS*16] | deg[N+1] | pairs[nbins*BIN_CAP+64] | h[(N+1)*64] bf16
// h row N = zero dummy row for predicated tail loads; deg[N] = 0 dummy.

__device__ __forceinline__ unsigned short f2bf(float f) {
    unsigned u = __float_as_uint(f);
    u += 0x7fffu + ((u >> 16) & 1u);     // round-to-nearest-even
    return (unsigned short)(u >> 16);
}
__device__ __forceinline__ float bf2f(unsigned short u) {
    return __uint_as_float((unsigned)u << 16);
}

// init: int64-vs-int32 edge detect, zero gcur + deg, zero dummy h row.
__global__ __launch_bounds__(256) void init_kernel(const int* __restrict__ ei32,
                                                   int* __restrict__ flag,
                                                   int* __restrict__ gcur,
                                                   int* __restrict__ deg,
                                                   unsigned short* __restrict__ h,
                                                   int N, int nbins) {
    int tid = threadIdx.x + blockIdx.x * 256;
    int stride = gridDim.x * 256;
    for (int i = tid; i < N + 1; i += stride) deg[i] = 0;
    for (int i = tid; i < nbins * GCUR_STRIDE; i += stride) gcur[i] = 0;
    if (blockIdx.x == 0) {
        __shared__ int any_nz;
        int t = threadIdx.x;
        if (t == 0) any_nz = 0;
        __syncthreads();
        int v = ei32[2 * t + 1];     // odd int32 words: all-zero iff nonneg int64 data
        if (v != 0) atomicOr(&any_nz, 1);
        if (t < 32) ((unsigned*)(h + (size_t)N * DIM))[t] = 0;   // dummy row
        __syncthreads();
        if (t == 0) *flag = (any_nz == 0) ? 1 : 0;
    }
}

union SmemK2 {
    struct { int h1[MAX_BINS]; int base[MAX_BINS]; } s;      // scatter role: 8 KB
    struct { float Wt[64 * 64]; float Xs[32 * GEMM_ROWS]; } g; // gemm role: 32 KB
};

// Fused pass: blocks [0,nchunks) scatter edges into dst-bins + accumulate global
// degree; blocks [nchunks,..) compute UNSCALED h = bf16(x @ W^T).  The two roles
// are data-independent so they overlap on the machine (all ~1027 blocks
// co-resident at 32 KB LDS -> 5 blocks/CU).
__global__ __launch_bounds__(256) void scatter_gemm_kernel(
    const void* __restrict__ ei, const int* __restrict__ flagp,
    int* __restrict__ gcur, int* __restrict__ pairs, int* __restrict__ deg,
    const float* __restrict__ x, const float* __restrict__ W,
    unsigned short* __restrict__ h,
    int E, int N, int nbins, int nchunks) {
    __shared__ SmemK2 sm;
    int tid = threadIdx.x;

    if (blockIdx.x < nchunks) {
        // ---------------- scatter role ----------------
        int is64 = *flagp;
        int chunk = blockIdx.x * CHUNK_EDGES;
        int ss[CHUNK_EDGES / 256], dd[CHUNK_EDGES / 256];

        for (int i = tid; i < nbins; i += 256) sm.s.h1[i] = 0;
        __syncthreads();
#pragma unroll
        for (int k = 0; k < CHUNK_EDGES / 256; ++k) {
            int i = chunk + k * 256 + tid;
            int s = 0, d = -1;
            if (i < E) {
                if (is64) {
                    s = (int)((const long long*)ei)[i];
                    d = (int)((const long long*)ei)[(long long)i + E];
                } else {
                    s = ((const int*)ei)[i];
                    d = ((const int*)ei)[i + E];
                }
                atomicAdd(&sm.s.h1[d >> BIN_SHIFT], 1);
                atomicAdd(&deg[d], 1);           // global in-degree (spread over 6250 lines)
            }
            ss[k] = s; dd[k] = d;
        }
        __syncthreads();
        for (int i = tid; i < nbins; i += 256) {
            int c = sm.s.h1[i];
            sm.s.base[i] = c ? (i * BIN_CAP + atomicAdd(&gcur[i * GCUR_STRIDE], c)) : 0;
            sm.s.h1[i] = 0;
        }
        __syncthreads();
#pragma unroll
        for (int k = 0; k < CHUNK_EDGES / 256; ++k) {
            if (dd[k] >= 0) {
                int bin = dd[k] >> BIN_SHIFT;
                int r = atomicAdd(&sm.s.h1[bin], 1);
                int pos = sm.s.base[bin] + r;
                if (pos < (bin + 1) * BIN_CAP)          // overflow guard (never expected)
                    pairs[pos] = (ss[k] << BIN_SHIFT) | (dd[k] & (NODES_PER_BIN - 1));
            }
        }
    } else {
        // ---------------- gemm role: h = bf16(x @ W^T), UNSCALED ----------------
        int row0 = (blockIdx.x - nchunks) * GEMM_ROWS;
        int nrows = min(GEMM_ROWS, N - row0);
#pragma unroll
        for (int t = 0; t < 16; ++t) {
            int i = t * 256 + tid;
            sm.g.Wt[i] = W[((i & 63) << 6) | (i >> 6)];   // Wt[k*64+c] = W[c*64+k]
        }
        const float* xbase = x + (size_t)row0 * DIM;
        int tc = tid & 7;
        int tr = tid >> 3;
        float acc[4][8] = {};
#pragma unroll
        for (int kh = 0; kh < 2; ++kh) {
            __syncthreads();   // kh=0: Wt visible; kh=1: prior compute done reading Xs
#pragma unroll
            for (int t = 0; t < 16; ++t) {
                int i = t * 256 + tid;                 // i = kl*128 + r
                int r = i & (GEMM_ROWS - 1);
                int k = (i >> 7) + 32 * kh;
                sm.g.Xs[i] = (r < nrows) ? xbase[r * DIM + k] : 0.0f;
            }
            __syncthreads();
#pragma unroll 4
            for (int kl = 0; kl < 32; ++kl) {
                int k = kl + 32 * kh;
                float4 xv = *(const float4*)&sm.g.Xs[kl * GEMM_ROWS + 4 * tr];
                float4 w0 = *(const float4*)&sm.g.Wt[k * 64 + 8 * tc];
                float4 w1 = *(const float4*)&sm.g.Wt[k * 64 + 8 * tc + 4];
                const float* xp = (const float*)&xv;
                const float* wp0 = (const float*)&w0;
                const float* wp1 = (const float*)&w1;
#pragma unroll
                for (int i = 0; i < 4; ++i) {
#pragma unroll
                    for (int j = 0; j < 4; ++j) {
                        acc[i][j] = fmaf(xp[i], wp0[j], acc[i][j]);
                        acc[i][4 + j] = fmaf(xp[i], wp1[j], acc[i][4 + j]);
                    }
                }
            }
        }
#pragma unroll
        for (int i = 0; i < 4; ++i) {
            int r = 4 * tr + i;
            if (r < nrows) {
                int g = row0 + r;
                ushort4 o0, o1;
                o0.x = f2bf(acc[i][0]); o0.y = f2bf(acc[i][1]);
                o0.z = f2bf(acc[i][2]); o0.w = f2bf(acc[i][3]);
                o1.x = f2bf(acc[i][4]); o1.y = f2bf(acc[i][5]);
                o1.z = f2bf(acc[i][6]); o1.w = f2bf(acc[i][7]);
                ushort4* hp = (ushort4*)(h + (size_t)g * DIM + 8 * tc);
                hp[0] = o0;
                hp[1] = o1;
            }
        }
    }
}

// Per-bin aggregate.  Messages fixed-pointed with +2^19 bias per term and packed
// 2-features-per-u64 -> 2 ds_add_u64 per edge-group (was 4 ds_add_u32).  dinv is
// computed on the fly from the global degree array (deg[src] is a 16-lane
// broadcast load); epilogue subtracts deg*B, adds self-loop + bias.
__global__ __launch_bounds__(256) void bin_aggregate_kernel(
    const unsigned short* __restrict__ h, const int* __restrict__ pairs,
    const int* __restrict__ gcur, const int* __restrict__ deg,
    const float* __restrict__ bias, float* __restrict__ out, int N) {
    __shared__ unsigned long long acc[NODES_PER_BIN * ACC_U64];   // 33 KB
    int b = blockIdx.x;
    int tid = threadIdx.x;
    int base = b * BIN_CAP;
    int cnt = min(gcur[b * GCUR_STRIDE], BIN_CAP);
    int node0 = b << BIN_SHIFT;
    int nn = min(NODES_PER_BIN, N - node0);

    for (int i = tid; i < NODES_PER_BIN * ACC_U64; i += 256) acc[i] = 0ULL;
    __syncthreads();

    int wave = tid >> 6, lane = tid & 63;
    int g = lane >> 4;                 // edge slot 0..3
    int fq = lane & 15;                // features 4*fq .. 4*fq+3
    const int* pb = pairs + base;
    int dummy = N << BIN_SHIFT;        // src=N (zero row / zero deg), predicated off

    for (int j0 = 32 * wave; j0 < cnt; j0 += 128) {
        int pk[8]; bool vd[8];
#pragma unroll
        for (int u = 0; u < 8; ++u) {
            int e = j0 + 4 * u + g;
            vd[u] = (e < cnt);                 // uniform per 16-lane group
            pk[u] = vd[u] ? pb[e] : dummy;
        }
        ushort4 r[8]; int dg[8];
#pragma unroll
        for (int u = 0; u < 8; ++u) {          // issue all gathers before use
            int src = pk[u] >> BIN_SHIFT;
            r[u] = *(const ushort4*)(h + src * DIM + 4 * fq);
            dg[u] = deg[src];
        }
#pragma unroll
        for (int u = 0; u < 8; ++u) {
            float mult = rsqrtf((float)(dg[u] + 1)) * FXSCALE;   // dinv[src] * 2^16 (exact x2^16)
            unsigned q0 = __float_as_uint(fmaf(bf2f(r[u].x), mult, MAGIC)) - (MAGIC_I - FXBIAS);
            unsigned q1 = __float_as_uint(fmaf(bf2f(r[u].y), mult, MAGIC)) - (MAGIC_I - FXBIAS);
            unsigned q2 = __float_as_uint(fmaf(bf2f(r[u].z), mult, MAGIC)) - (MAGIC_I - FXBIAS);
            unsigned q3 = __float_as_uint(fmaf(bf2f(r[u].w), mult, MAGIC)) - (MAGIC_I - FXBIAS);
            if (vd[u]) {
                unsigned long long* ar =
                    &acc[(pk[u] & (NODES_PER_BIN - 1)) * ACC_U64 + 2 * fq];
                atomicAdd(&ar[0], (unsigned long long)q0 | ((unsigned long long)q1 << 32));
                atomicAdd(&ar[1], (unsigned long long)q2 | ((unsigned long long)q3 << 32));
            }
        }
    }
    __syncthreads();

    // dword view: feature f of node ld lives at dword [ld*66 + f]
    const int* accd = (const int*)acc;
    for (int ld = wave; ld < nn; ld += 4) {
        int gn = node0 + ld;                                // wave-uniform
        int dgn = deg[gn];
        float di = rsqrtf((float)(dgn + 1));
        unsigned q = (unsigned)accd[ld * (2 * ACC_U64) + lane];
        int sfx = (int)(q - (unsigned)dgn * FXBIAS);        // remove per-term bias
        float sum = (float)sfx * FXINV;
        float self = bf2f(h[(size_t)gn * DIM + lane]);      // unscaled h
        out[(size_t)gn * DIM + lane] = (sum + self * di) * di + bias[lane];
    }
}

extern "C" void kernel_launch(void* const* d_in, const int* in_sizes, int n_in,
                              void* d_out, int out_size, void* d_ws, size_t ws_size,
                              hipStream_t stream) {
    const float* x = (const float*)d_in[0];
    const void* ei = d_in[1];
    const float* W = (const float*)d_in[2];
    const float* b = (const float*)d_in[3];
    float* out = (float*)d_out;

    int N = in_sizes[0] / DIM;   // 100000
    int E = in_sizes[1] / 2;     // 1000000
    int nbins = (N + NODES_PER_BIN - 1) >> BIN_SHIFT;   // 782

    char* ws = (char*)d_ws;
    auto align256 = [](size_t v) { return (v + 255) & ~(size_t)255; };
    size_t off = 0;
    int* flag = (int*)(ws + off);              off = align256(off + 4);
    int* gcur = (int*)(ws + off);              off = align256(off + (size_t)MAX_BINS * GCUR_STRIDE * 4);
    int* deg  = (int*)(ws + off);              off = align256(off + (size_t)(N + 1) * 4);
    int* pairs = (int*)(ws + off);             off = align256(off + ((size_t)nbins * BIN_CAP + 64) * 4);
    unsigned short* h = (unsigned short*)(ws + off); off = align256(off + (size_t)(N + 1) * DIM * 2);

    int nchunks = (E + CHUNK_EDGES - 1) / CHUNK_EDGES;       // 245
    int gemmblocks = (N + GEMM_ROWS - 1) / GEMM_ROWS;        // 782

    init_kernel<<<64, 256, 0, stream>>>((const int*)ei, flag, gcur, deg, h, N, nbins);
    scatter_gemm_kernel<<<nchunks + gemmblocks, 256, 0, stream>>>(
        ei, flag, gcur, pairs, deg, x, W, h, E, N, nbins, nchunks);
    bin_aggregate_kernel<<<nbins, 256, 0, stream>>>(h, pairs, gcur, deg, b, out, N);
}

// Round 2
// 176.858 us; speedup vs baseline: 1.0755x; 1.0755x over previous
//
#include <hip/hip_runtime.h>

#define DIM 64
#define BIN_SHIFT 7                  // 128 nodes per bin
#define NODES_PER_BIN 128
#define MAX_BINS 1024                // ceil(100000/128)=782 <= 1024
#define BIN_CAP 2048                 // mean 1279, sigma ~36 -> 21-sigma margin
#define CHUNK_EDGES 2048             // edges per scatter block (4096 regressed: per-block latency)
#define GEMM_ROWS 128                // rows per gemm-role block
#define FXSCALE 65536.0f             // fixed-point scale 2^16
#define FXINV (1.0f / 65536.0f)
#define FXBIAS 524288u               // 2^19 per-term bias keeps each term non-negative (|v|<8)
#define MAGIC 12582912.0f            // 1.5*2^23 RNE float->int magic
#define MAGIC_I 0x4B400000u
#define GCUR_STRIDE 16               // one cacheline per bin counter
#define ACC_U64 33                   // u64 per node: 32 used + 1 pad

// ws layout (256-aligned):
// flag | gcur[MAX_BINS*16] | deg[N+1] | dinv[N+1] | pairs[nbins*BIN_CAP+64] | h[(N+1)*64] bf16
// h row N = zero dummy row for predicated tail loads; deg/dinv[N] read-only dummies.

__device__ __forceinline__ unsigned short f2bf(float f) {
    unsigned u = __float_as_uint(f);
    u += 0x7fffu + ((u >> 16) & 1u);     // round-to-nearest-even
    return (unsigned short)(u >> 16);
}
__device__ __forceinline__ float bf2f(unsigned short u) {
    return __uint_as_float((unsigned)u << 16);
}

// init: int64-vs-int32 edge detect, zero gcur, zero dummy h row.
__global__ __launch_bounds__(256) void init_kernel(const int* __restrict__ ei32,
                                                   int* __restrict__ flag,
                                                   int* __restrict__ gcur,
                                                   unsigned short* __restrict__ h,
                                                   int N, int nbins) {
    int tid = threadIdx.x + blockIdx.x * 256;
    int stride = gridDim.x * 256;
    for (int i = tid; i < nbins * GCUR_STRIDE; i += stride) gcur[i] = 0;
    if (blockIdx.x == 0) {
        __shared__ int any_nz;
        int t = threadIdx.x;
        if (t == 0) any_nz = 0;
        __syncthreads();
        int v = ei32[2 * t + 1];     // odd int32 words: all-zero iff nonneg int64 data
        if (v != 0) atomicOr(&any_nz, 1);
        if (t < 32) ((unsigned*)(h + (size_t)N * DIM))[t] = 0;   // dummy row
        __syncthreads();
        if (t == 0) *flag = (any_nz == 0) ? 1 : 0;
    }
}

union SmemK2 {
    struct { int h1[MAX_BINS]; int base[MAX_BINS]; } s;        // scatter role: 8 KB
    struct { float Wt[64 * 64]; float Xs[32 * GEMM_ROWS]; } g; // gemm role: 32 KB
};

// Fused pass: blocks [0,nchunks) scatter edges into dst-bins; blocks [nchunks,..)
// compute UNSCALED h = bf16(x @ W^T).  Data-independent roles overlap on the
// machine (1271 blocks, 5/CU at 32 KB LDS -> all co-resident).
__global__ __launch_bounds__(256) void scatter_gemm_kernel(
    const void* __restrict__ ei, const int* __restrict__ flagp,
    int* __restrict__ gcur, int* __restrict__ pairs,
    const float* __restrict__ x, const float* __restrict__ W,
    unsigned short* __restrict__ h,
    int E, int N, int nbins, int nchunks) {
    __shared__ SmemK2 sm;
    int tid = threadIdx.x;

    if (blockIdx.x < nchunks) {
        // ---------------- scatter role (round-0-proven shape) ----------------
        int is64 = *flagp;
        int chunk = blockIdx.x * CHUNK_EDGES;
        int ss[CHUNK_EDGES / 256], dd[CHUNK_EDGES / 256];

        for (int i = tid; i < nbins; i += 256) sm.s.h1[i] = 0;
        __syncthreads();
#pragma unroll
        for (int k = 0; k < CHUNK_EDGES / 256; ++k) {
            int i = chunk + k * 256 + tid;
            int s = 0, d = -1;
            if (i < E) {
                if (is64) {
                    s = (int)((const long long*)ei)[i];
                    d = (int)((const long long*)ei)[(long long)i + E];
                } else {
                    s = ((const int*)ei)[i];
                    d = ((const int*)ei)[i + E];
                }
                atomicAdd(&sm.s.h1[d >> BIN_SHIFT], 1);
            }
            ss[k] = s; dd[k] = d;
        }
        __syncthreads();
        for (int i = tid; i < nbins; i += 256) {
            int c = sm.s.h1[i];
            sm.s.base[i] = c ? (i * BIN_CAP + atomicAdd(&gcur[i * GCUR_STRIDE], c)) : 0;
            sm.s.h1[i] = 0;
        }
        __syncthreads();
#pragma unroll
        for (int k = 0; k < CHUNK_EDGES / 256; ++k) {
            if (dd[k] >= 0) {
                int bin = dd[k] >> BIN_SHIFT;
                int r = atomicAdd(&sm.s.h1[bin], 1);
                int pos = sm.s.base[bin] + r;
                if (pos < (bin + 1) * BIN_CAP)          // overflow guard (never expected)
                    pairs[pos] = (ss[k] << BIN_SHIFT) | (dd[k] & (NODES_PER_BIN - 1));
            }
        }
    } else {
        // ---------------- gemm role: h = bf16(x @ W^T), UNSCALED ----------------
        int row0 = (blockIdx.x - nchunks) * GEMM_ROWS;
        int nrows = min(GEMM_ROWS, N - row0);
#pragma unroll
        for (int t = 0; t < 16; ++t) {
            int i = t * 256 + tid;
            sm.g.Wt[i] = W[((i & 63) << 6) | (i >> 6)];   // Wt[k*64+c] = W[c*64+k]
        }
        const float* xbase = x + (size_t)row0 * DIM;
        int tc = tid & 7;
        int tr = tid >> 3;
        float acc[4][8] = {};
#pragma unroll
        for (int kh = 0; kh < 2; ++kh) {
            __syncthreads();   // kh=0: Wt visible; kh=1: prior compute done reading Xs
#pragma unroll
            for (int t = 0; t < 16; ++t) {
                int i = t * 256 + tid;                 // i = kl*128 + r
                int r = i & (GEMM_ROWS - 1);
                int k = (i >> 7) + 32 * kh;
                sm.g.Xs[i] = (r < nrows) ? xbase[r * DIM + k] : 0.0f;
            }
            __syncthreads();
#pragma unroll 4
            for (int kl = 0; kl < 32; ++kl) {
                int k = kl + 32 * kh;
                float4 xv = *(const float4*)&sm.g.Xs[kl * GEMM_ROWS + 4 * tr];
                float4 w0 = *(const float4*)&sm.g.Wt[k * 64 + 8 * tc];
                float4 w1 = *(const float4*)&sm.g.Wt[k * 64 + 8 * tc + 4];
                const float* xp = (const float*)&xv;
                const float* wp0 = (const float*)&w0;
                const float* wp1 = (const float*)&w1;
#pragma unroll
                for (int i = 0; i < 4; ++i) {
#pragma unroll
                    for (int j = 0; j < 4; ++j) {
                        acc[i][j] = fmaf(xp[i], wp0[j], acc[i][j]);
                        acc[i][4 + j] = fmaf(xp[i], wp1[j], acc[i][4 + j]);
                    }
                }
            }
        }
#pragma unroll
        for (int i = 0; i < 4; ++i) {
            int r = 4 * tr + i;
            if (r < nrows) {
                int g = row0 + r;
                ushort4 o0, o1;
                o0.x = f2bf(acc[i][0]); o0.y = f2bf(acc[i][1]);
                o0.z = f2bf(acc[i][2]); o0.w = f2bf(acc[i][3]);
                o1.x = f2bf(acc[i][4]); o1.y = f2bf(acc[i][5]);
                o1.z = f2bf(acc[i][6]); o1.w = f2bf(acc[i][7]);
                ushort4* hp = (ushort4*)(h + (size_t)g * DIM + 8 * tc);
                hp[0] = o0;
                hp[1] = o1;
            }
        }
    }
}

// Per-bin degree histogram -> deg (int, for bias subtract) + dinv (float).
// Bin holds ALL in-edges of its nodes.  Coalesced pairs read, LDS int atomics.
__global__ __launch_bounds__(256) void degree_kernel(const int* __restrict__ pairs,
                                                     const int* __restrict__ gcur,
                                                     int* __restrict__ deg,
                                                     float* __restrict__ dinv, int N) {
    __shared__ int sdeg[NODES_PER_BIN];
    int b = blockIdx.x;
    int tid = threadIdx.x;
    int base = b * BIN_CAP;
    int cnt = min(gcur[b * GCUR_STRIDE], BIN_CAP);
    int node0 = b << BIN_SHIFT;
    int nn = min(NODES_PER_BIN, N - node0);
    if (tid < NODES_PER_BIN) sdeg[tid] = 0;
    __syncthreads();
    for (int i = tid; i < cnt; i += 256)
        atomicAdd(&sdeg[pairs[base + i] & (NODES_PER_BIN - 1)], 1);
    __syncthreads();
    if (tid < nn) {
        int d = sdeg[tid];
        deg[node0 + tid] = d;
        dinv[node0 + tid] = rsqrtf((float)(d + 1));   // +1 self-loop
    }
}

// Per-bin aggregate.  Messages fixed-pointed with +2^19 bias per term, packed
// 2-features-per-u64 -> 2 ds_add_u64 per edge-group.  dinv[src] gathered as
// float; epilogue subtracts deg*BIAS, adds self-loop + bias.
__global__ __launch_bounds__(256) void bin_aggregate_kernel(
    const unsigned short* __restrict__ h, const int* __restrict__ pairs,
    const int* __restrict__ gcur, const int* __restrict__ deg,
    const float* __restrict__ dinv,
    const float* __restrict__ bias, float* __restrict__ out, int N) {
    __shared__ unsigned long long acc[NODES_PER_BIN * ACC_U64];   // 33 KB
    int b = blockIdx.x;
    int tid = threadIdx.x;
    int base = b * BIN_CAP;
    int cnt = min(gcur[b * GCUR_STRIDE], BIN_CAP);
    int node0 = b << BIN_SHIFT;
    int nn = min(NODES_PER_BIN, N - node0);

    for (int i = tid; i < NODES_PER_BIN * ACC_U64; i += 256) acc[i] = 0ULL;
    __syncthreads();

    int wave = tid >> 6, lane = tid & 63;
    int g = lane >> 4;                 // edge slot 0..3
    int fq = lane & 15;                // features 4*fq .. 4*fq+3
    const int* pb = pairs + base;
    int dummy = N << BIN_SHIFT;        // src=N (zero row), predicated off

    for (int j0 = 32 * wave; j0 < cnt; j0 += 128) {
        int pk[8]; bool vd[8];
#pragma unroll
        for (int u = 0; u < 8; ++u) {
            int e = j0 + 4 * u + g;
            vd[u] = (e < cnt);                 // uniform per 16-lane group
            pk[u] = vd[u] ? pb[e] : dummy;
        }
        ushort4 r[8]; float dv[8];
#pragma unroll
        for (int u = 0; u < 8; ++u) {          // issue all gathers before use
            int src = pk[u] >> BIN_SHIFT;
            r[u] = *(const ushort4*)(h + (size_t)src * DIM + 4 * fq);
            dv[u] = dinv[src];
        }
#pragma unroll
        for (int u = 0; u < 8; ++u) {
            float mult = dv[u] * FXSCALE;      // dinv[src] * 2^16 (exact pow2 scale)
            unsigned q0 = __float_as_uint(fmaf(bf2f(r[u].x), mult, MAGIC)) - (MAGIC_I - FXBIAS);
            unsigned q1 = __float_as_uint(fmaf(bf2f(r[u].y), mult, MAGIC)) - (MAGIC_I - FXBIAS);
            unsigned q2 = __float_as_uint(fmaf(bf2f(r[u].z), mult, MAGIC)) - (MAGIC_I - FXBIAS);
            unsigned q3 = __float_as_uint(fmaf(bf2f(r[u].w), mult, MAGIC)) - (MAGIC_I - FXBIAS);
            if (vd[u]) {
                unsigned long long* ar =
                    &acc[(pk[u] & (NODES_PER_BIN - 1)) * ACC_U64 + 2 * fq];
                atomicAdd(&ar[0], (unsigned long long)q0 | ((unsigned long long)q1 << 32));
                atomicAdd(&ar[1], (unsigned long long)q2 | ((unsigned long long)q3 << 32));
            }
        }
    }
    __syncthreads();

    // dword view: feature f of node ld lives at dword [ld*66 + f]
    const int* accd = (const int*)acc;
    for (int ld = wave; ld < nn; ld += 4) {
        int gn = node0 + ld;                                // wave-uniform
        int dgn = deg[gn];
        float di = dinv[gn];
        unsigned q = (unsigned)accd[ld * (2 * ACC_U64) + lane];
        int sfx = (int)(q - (unsigned)dgn * FXBIAS);        // remove per-term bias
        float sum = (float)sfx * FXINV;
        float self = bf2f(h[(size_t)gn * DIM + lane]);      // unscaled h
        out[(size_t)gn * DIM + lane] = (sum + self * di) * di + bias[lane];
    }
}

extern "C" void kernel_launch(void* const* d_in, const int* in_sizes, int n_in,
                              void* d_out, int out_size, void* d_ws, size_t ws_size,
                              hipStream_t stream) {
    const float* x = (const float*)d_in[0];
    const void* ei = d_in[1];
    const float* W = (const float*)d_in[2];
    const float* b = (const float*)d_in[3];
    float* out = (float*)d_out;

    int N = in_sizes[0] / DIM;   // 100000
    int E = in_sizes[1] / 2;     // 1000000
    int nbins = (N + NODES_PER_BIN - 1) >> BIN_SHIFT;   // 782

    char* ws = (char*)d_ws;
    auto align256 = [](size_t v) { return (v + 255) & ~(size_t)255; };
    size_t off = 0;
    int* flag = (int*)(ws + off);              off = align256(off + 4);
    int* gcur = (int*)(ws + off);              off = align256(off + (size_t)MAX_BINS * GCUR_STRIDE * 4);
    int* deg  = (int*)(ws + off);              off = align256(off + (size_t)(N + 1) * 4);
    float* dinv = (float*)(ws + off);          off = align256(off + (size_t)(N + 1) * 4);
    int* pairs = (int*)(ws + off);             off = align256(off + ((size_t)nbins * BIN_CAP + 64) * 4);
    unsigned short* h = (unsigned short*)(ws + off); off = align256(off + (size_t)(N + 1) * DIM * 2);

    int nchunks = (E + CHUNK_EDGES - 1) / CHUNK_EDGES;       // 489
    int gemmblocks = (N + GEMM_ROWS - 1) / GEMM_ROWS;        // 782

    init_kernel<<<64, 256, 0, stream>>>((const int*)ei, flag, gcur, h, N, nbins);
    scatter_gemm_kernel<<<nchunks + gemmblocks, 256, 0, stream>>>(
        ei, flag, gcur, pairs, x, W, h, E, N, nbins, nchunks);
    degree_kernel<<<nbins, 256, 0, stream>>>(pairs, gcur, deg, dinv, N);
    bin_aggregate_kernel<<<nbins, 256, 0, stream>>>(h, pairs, gcur, deg, dinv, b, out, N);
}